// Round 2
// baseline (1020.167 us; speedup 1.0000x reference)
//
#include <hip/hip_runtime.h>

#define NB 4
#define SEQ 1024
#define NH 32
#define NKV 8
#define HD 64
#define QBLK 32
#define VSTR 72   // VsT row stride in ushorts (144B, 16B-aligned)

typedef __attribute__((ext_vector_type(8))) short short8;
typedef __attribute__((ext_vector_type(4))) float f32x4;

__device__ __forceinline__ unsigned short f2bf(float f) {
  union { float f; unsigned u; } x; x.f = f;
  unsigned u = x.u;
  u += 0x7fffu + ((u >> 16) & 1u);   // round-to-nearest-even
  return (unsigned short)(u >> 16);
}
__device__ __forceinline__ float bf2f(unsigned short h) {
  union { unsigned u; float f; } x; x.u = ((unsigned)h) << 16;
  return x.f;
}

__global__ __launch_bounds__(256, 2) void gqa_kernel(
    const float* __restrict__ Qg, const float* __restrict__ Kg,
    const float* __restrict__ Vg, float* __restrict__ Og) {
  __shared__ unsigned short Plds[QBLK * SEQ];   // 64KB bf16 P, XOR-swizzled
  __shared__ unsigned short VsT[HD * VSTR];     // 9216B V^T chunk [d][k]
  __shared__ float redmax[QBLK][4];
  __shared__ float redsum[QBLK][4];

  const int tid = threadIdx.x;
  const int lane = tid & 63;
  const int wid = tid >> 6;
  const int li = lane & 15;
  const int g = lane >> 4;

  // XCD-aware bijective swizzle: 4096 blocks, 8 XCDs -> 512 contiguous each.
  const int hw = blockIdx.x;
  const int gid = (hw & 7) * 512 + (hw >> 3);

  const int qt = gid & 31;
  const int h = (gid >> 5) & 31;
  const int b = gid >> 10;
  const int hkv = h >> 2;
  const int q0 = qt * QBLK;

  const float* Qp = Qg + ((size_t)b * SEQ) * 2048 + h * 64;
  const float* Kp = Kg + ((size_t)b * SEQ) * 512 + hkv * 64;
  const float* Vp = Vg + ((size_t)b * SEQ) * 512 + hkv * 64;
  float* Outp = Og + ((size_t)b * SEQ) * 2048 + h * 64;
  float* Attnp = Og + (size_t)NB * SEQ * 2048
               + (((size_t)(b * NH + h)) * SEQ + q0) * SEQ;

  char* pb = (char*)&Plds[0];

  // ---- Q fragments, scale 1/8 folded in fp32 (exact, power of 2) ----
  short8 aq[2][2];
#pragma unroll
  for (int m = 0; m < 2; ++m)
#pragma unroll
    for (int dh = 0; dh < 2; ++dh) {
      const float* qp = Qp + (size_t)(q0 + m * 16 + li) * 2048 + dh * 32 + g * 8;
      float4 x = *(const float4*)qp;
      float4 y = *(const float4*)(qp + 4);
      short8 t;
      t[0] = (short)f2bf(x.x * 0.125f); t[1] = (short)f2bf(x.y * 0.125f);
      t[2] = (short)f2bf(x.z * 0.125f); t[3] = (short)f2bf(x.w * 0.125f);
      t[4] = (short)f2bf(y.x * 0.125f); t[5] = (short)f2bf(y.y * 0.125f);
      t[6] = (short)f2bf(y.z * 0.125f); t[7] = (short)f2bf(y.w * 0.125f);
      aq[m][dh] = t;
    }

  // ---- QK^T: wave owns cols [wid*256, wid*256+256) ----
  f32x4 acc[2][16];
  f32x4 zero4 = {0.f, 0.f, 0.f, 0.f};
#pragma unroll
  for (int m = 0; m < 2; ++m)
#pragma unroll
    for (int j = 0; j < 16; ++j) acc[m][j] = zero4;

  const int colbase = wid * 256 + li;
#pragma unroll 4
  for (int j = 0; j < 16; ++j) {
    int col = colbase + j * 16;
    short8 bk[2];
#pragma unroll
    for (int dh = 0; dh < 2; ++dh) {
      const float* kp = Kp + (size_t)col * 512 + dh * 32 + g * 8;
      float4 x = *(const float4*)kp;
      float4 y = *(const float4*)(kp + 4);
      short8 t;
      t[0]=(short)f2bf(x.x); t[1]=(short)f2bf(x.y); t[2]=(short)f2bf(x.z); t[3]=(short)f2bf(x.w);
      t[4]=(short)f2bf(y.x); t[5]=(short)f2bf(y.y); t[6]=(short)f2bf(y.z); t[7]=(short)f2bf(y.w);
      bk[dh] = t;
    }
#pragma unroll
    for (int m = 0; m < 2; ++m) {
      acc[m][j] = __builtin_amdgcn_mfma_f32_16x16x32_bf16(aq[m][0], bk[0], acc[m][j], 0, 0, 0);
      acc[m][j] = __builtin_amdgcn_mfma_f32_16x16x32_bf16(aq[m][1], bk[1], acc[m][j], 0, 0, 0);
    }
  }

  // ---- softmax: C layout row=(lane>>4)*4+r, col=lane&15 ----
#pragma unroll
  for (int m = 0; m < 2; ++m)
#pragma unroll
    for (int r = 0; r < 4; ++r) {
      float mx = -1e30f;
#pragma unroll
      for (int j = 0; j < 16; ++j) mx = fmaxf(mx, acc[m][j][r]);
      mx = fmaxf(mx, __shfl_xor(mx, 1));
      mx = fmaxf(mx, __shfl_xor(mx, 2));
      mx = fmaxf(mx, __shfl_xor(mx, 4));
      mx = fmaxf(mx, __shfl_xor(mx, 8));
      if (li == 0) redmax[m * 16 + g * 4 + r][wid] = mx;
    }
  __syncthreads();

#pragma unroll
  for (int m = 0; m < 2; ++m)
#pragma unroll
    for (int r = 0; r < 4; ++r) {
      int row = m * 16 + g * 4 + r;
      float mx = fmaxf(fmaxf(redmax[row][0], redmax[row][1]),
                       fmaxf(redmax[row][2], redmax[row][3]));
      float s = 0.f;
#pragma unroll
      for (int j = 0; j < 16; ++j) {
        float e = __expf(acc[m][j][r] - mx);
        acc[m][j][r] = e;
        s += e;
      }
      s += __shfl_xor(s, 1);
      s += __shfl_xor(s, 2);
      s += __shfl_xor(s, 4);
      s += __shfl_xor(s, 8);
      if (li == 0) redsum[row][wid] = s;
    }
  __syncthreads();

  // ---- normalize; write P (bf16 LDS, swizzled) only ----
#pragma unroll
  for (int m = 0; m < 2; ++m)
#pragma unroll
    for (int r = 0; r < 4; ++r) {
      int row = m * 16 + g * 4 + r;
      float L = redsum[row][0] + redsum[row][1] + redsum[row][2] + redsum[row][3];
      float inv = 1.0f / L;
#pragma unroll
      for (int j = 0; j < 16; ++j) {
        float p = acc[m][j][r] * inv;
        int col = colbase + j * 16;
        *(unsigned short*)(pb + (((row << 11) + (col << 1)) ^ ((row & 7) << 4))) = f2bf(p);
      }
    }
  __syncthreads();

  // ---- attn store from Plds: full-line coalesced float4 writes ----
  // iteration i: 256 threads cover row i, cols tid*4..tid*4+3 (4KB row/iter)
#pragma unroll 4
  for (int i = 0; i < QBLK; ++i) {
    int byte = (((i << 11) + (tid << 3)) ^ ((i & 7) << 4));
    ushort4 u = *(const ushort4*)(pb + byte);
    float4 f;
    f.x = bf2f(u.x); f.y = bf2f(u.y); f.z = bf2f(u.z); f.w = bf2f(u.w);
    *(float4*)(Attnp + (size_t)i * SEQ + tid * 4) = f;
  }

  // ---- PV: wave -> out rows m_o*16..+15, cols nb_..nb_+31, full K ----
  const int m_o = wid >> 1;
  const int nb_ = (wid & 1) * 32;
  f32x4 acc0 = zero4, acc1 = zero4;

  for (int c = 0; c < 16; ++c) {
    // stage V chunk transposed: VsT[d][k_local], 64 k-rows, b64 writes
    {
      const int kd = tid & 63;
      const int kg = tid >> 6;
      const float* vcol = Vp + (size_t)(c * 64 + kg * 16) * 512 + kd;
#pragma unroll
      for (int t4 = 0; t4 < 4; ++t4) {
        ushort4 w;
        w.x = f2bf(vcol[(size_t)(t4 * 4 + 0) * 512]);
        w.y = f2bf(vcol[(size_t)(t4 * 4 + 1) * 512]);
        w.z = f2bf(vcol[(size_t)(t4 * 4 + 2) * 512]);
        w.w = f2bf(vcol[(size_t)(t4 * 4 + 3) * 512]);
        *(ushort4*)(&VsT[kd * VSTR + kg * 16 + t4 * 4]) = w;
      }
    }
    __syncthreads();

#pragma unroll
    for (int kt = 0; kt < 2; ++kt) {
      int colk = c * 64 + kt * 32 + g * 8;
      int prow = m_o * 16 + li;
      short8 pa = *(const short8*)(pb + (((prow << 11) + (colk << 1)) ^ ((prow & 7) << 4)));
#pragma unroll
      for (int nn = 0; nn < 2; ++nn) {
        int d = nb_ + nn * 16 + li;
        short8 vbf = *(const short8*)(&VsT[d * VSTR + kt * 32 + g * 8]);
        if (nn == 0) acc0 = __builtin_amdgcn_mfma_f32_16x16x32_bf16(pa, vbf, acc0, 0, 0, 0);
        else         acc1 = __builtin_amdgcn_mfma_f32_16x16x32_bf16(pa, vbf, acc1, 0, 0, 0);
      }
    }
    __syncthreads();
  }

  // ---- epilogue: out[q0+m_o*16+g*4+r][nb_ + nn*16 + li] ----
#pragma unroll
  for (int r = 0; r < 4; ++r) {
    int row = q0 + m_o * 16 + g * 4 + r;
    Outp[(size_t)row * 2048 + nb_ + li] = acc0[r];
    Outp[(size_t)row * 2048 + nb_ + 16 + li] = acc1[r];
  }
}

extern "C" void kernel_launch(void* const* d_in, const int* in_sizes, int n_in,
                              void* d_out, int out_size, void* d_ws, size_t ws_size,
                              hipStream_t stream) {
  const float* q = (const float*)d_in[0];
  const float* k = (const float*)d_in[1];
  const float* v = (const float*)d_in[2];
  float* o = (float*)d_out;
  dim3 grid(NB * NH * (SEQ / QBLK));  // 4096
  dim3 block(256);
  hipLaunchKernelGGL(gqa_kernel, grid, block, 0, stream, q, k, v, o);
}

// Round 3
// 870.998 us; speedup vs baseline: 1.1713x; 1.1713x over previous
//
#include <hip/hip_runtime.h>

#define NB 4
#define SEQ 1024
#define NH 32
#define NKV 8
#define HD 64
#define QBLK 32
#define VSTR 72   // VsT row stride in ushorts (144B, 16B-aligned)

typedef __attribute__((ext_vector_type(8))) short short8;
typedef __attribute__((ext_vector_type(4))) float f32x4;

__device__ __forceinline__ unsigned short f2bf(float f) {
  union { float f; unsigned u; } x; x.f = f;
  unsigned u = x.u;
  u += 0x7fffu + ((u >> 16) & 1u);   // round-to-nearest-even
  return (unsigned short)(u >> 16);
}

__global__ __launch_bounds__(256, 2) void gqa_kernel(
    const float* __restrict__ Qg, const float* __restrict__ Kg,
    const float* __restrict__ Vg, float* __restrict__ Og) {
  __shared__ unsigned short Plds[QBLK * SEQ];   // 64KB bf16 P, XOR-swizzled
  __shared__ unsigned short VsT[HD * VSTR];     // 9216B V^T chunk [d][k]
  __shared__ float redmax[QBLK][4];
  __shared__ float redsum[QBLK][4];

  const int tid = threadIdx.x;
  const int lane = tid & 63;
  const int wid = tid >> 6;
  const int li = lane & 15;
  const int g = lane >> 4;

  // XCD-aware bijective swizzle: 4096 blocks, 8 XCDs -> 512 contiguous each.
  const int hw = blockIdx.x;
  const int gid = (hw & 7) * 512 + (hw >> 3);

  const int qt = gid & 31;
  const int h = (gid >> 5) & 31;
  const int b = gid >> 10;
  const int hkv = h >> 2;
  const int q0 = qt * QBLK;

  const float* Qp = Qg + ((size_t)b * SEQ) * 2048 + h * 64;
  const float* Kp = Kg + ((size_t)b * SEQ) * 512 + hkv * 64;
  const float* Vp = Vg + ((size_t)b * SEQ) * 512 + hkv * 64;
  float* Outp = Og + ((size_t)b * SEQ) * 2048 + h * 64;
  float* Attnp = Og + (size_t)NB * SEQ * 2048
               + (((size_t)(b * NH + h)) * SEQ + q0) * SEQ;

  char* pb = (char*)&Plds[0];

  // ---- Q fragments, scale 1/8 folded in fp32 (exact, power of 2) ----
  short8 aq[2][2];
#pragma unroll
  for (int m = 0; m < 2; ++m)
#pragma unroll
    for (int dh = 0; dh < 2; ++dh) {
      const float* qp = Qp + (size_t)(q0 + m * 16 + li) * 2048 + dh * 32 + g * 8;
      float4 x = *(const float4*)qp;
      float4 y = *(const float4*)(qp + 4);
      short8 t;
      t[0] = (short)f2bf(x.x * 0.125f); t[1] = (short)f2bf(x.y * 0.125f);
      t[2] = (short)f2bf(x.z * 0.125f); t[3] = (short)f2bf(x.w * 0.125f);
      t[4] = (short)f2bf(y.x * 0.125f); t[5] = (short)f2bf(y.y * 0.125f);
      t[6] = (short)f2bf(y.z * 0.125f); t[7] = (short)f2bf(y.w * 0.125f);
      aq[m][dh] = t;
    }

  // ---- QK^T: wave owns cols [wid*256, wid*256+256) ----
  f32x4 acc[2][16];
  f32x4 zero4 = {0.f, 0.f, 0.f, 0.f};
#pragma unroll
  for (int m = 0; m < 2; ++m)
#pragma unroll
    for (int j = 0; j < 16; ++j) acc[m][j] = zero4;

  const int colbase = wid * 256 + li;
#pragma unroll 4
  for (int j = 0; j < 16; ++j) {
    int col = colbase + j * 16;
    short8 bk[2];
#pragma unroll
    for (int dh = 0; dh < 2; ++dh) {
      const float* kp = Kp + (size_t)col * 512 + dh * 32 + g * 8;
      float4 x = *(const float4*)kp;
      float4 y = *(const float4*)(kp + 4);
      short8 t;
      t[0]=(short)f2bf(x.x); t[1]=(short)f2bf(x.y); t[2]=(short)f2bf(x.z); t[3]=(short)f2bf(x.w);
      t[4]=(short)f2bf(y.x); t[5]=(short)f2bf(y.y); t[6]=(short)f2bf(y.z); t[7]=(short)f2bf(y.w);
      bk[dh] = t;
    }
#pragma unroll
    for (int m = 0; m < 2; ++m) {
      acc[m][j] = __builtin_amdgcn_mfma_f32_16x16x32_bf16(aq[m][0], bk[0], acc[m][j], 0, 0, 0);
      acc[m][j] = __builtin_amdgcn_mfma_f32_16x16x32_bf16(aq[m][1], bk[1], acc[m][j], 0, 0, 0);
    }
  }

  // ---- softmax: C layout row=(lane>>4)*4+r, col=lane&15 ----
#pragma unroll
  for (int m = 0; m < 2; ++m)
#pragma unroll
    for (int r = 0; r < 4; ++r) {
      float mx = -1e30f;
#pragma unroll
      for (int j = 0; j < 16; ++j) mx = fmaxf(mx, acc[m][j][r]);
      mx = fmaxf(mx, __shfl_xor(mx, 1));
      mx = fmaxf(mx, __shfl_xor(mx, 2));
      mx = fmaxf(mx, __shfl_xor(mx, 4));
      mx = fmaxf(mx, __shfl_xor(mx, 8));
      if (li == 0) redmax[m * 16 + g * 4 + r][wid] = mx;
    }
  __syncthreads();

#pragma unroll
  for (int m = 0; m < 2; ++m)
#pragma unroll
    for (int r = 0; r < 4; ++r) {
      int row = m * 16 + g * 4 + r;
      float mx = fmaxf(fmaxf(redmax[row][0], redmax[row][1]),
                       fmaxf(redmax[row][2], redmax[row][3]));
      float s = 0.f;
#pragma unroll
      for (int j = 0; j < 16; ++j) {
        float e = __expf(acc[m][j][r] - mx);
        acc[m][j][r] = e;
        s += e;
      }
      s += __shfl_xor(s, 1);
      s += __shfl_xor(s, 2);
      s += __shfl_xor(s, 4);
      s += __shfl_xor(s, 8);
      if (li == 0) redsum[row][wid] = s;
    }
  __syncthreads();

  // ---- normalize; attn nt-store from regs + P (bf16 LDS, swizzled) ----
#pragma unroll
  for (int m = 0; m < 2; ++m)
#pragma unroll
    for (int r = 0; r < 4; ++r) {
      int row = m * 16 + g * 4 + r;
      float L = redsum[row][0] + redsum[row][1] + redsum[row][2] + redsum[row][3];
      float inv = 1.0f / L;
      float* arow = Attnp + (size_t)row * SEQ + colbase;
#pragma unroll
      for (int j = 0; j < 16; ++j) {
        float p = acc[m][j][r] * inv;
        __builtin_nontemporal_store(p, arow + j * 16);
        int col = colbase + j * 16;
        *(unsigned short*)(pb + (((row << 11) + (col << 1)) ^ ((row & 7) << 4))) = f2bf(p);
      }
    }
  __syncthreads();

  // ---- PV: wave -> out rows m_o*16..+15, cols nb_..nb_+31, full K ----
  const int m_o = wid >> 1;
  const int nb_ = (wid & 1) * 32;
  f32x4 acc0 = zero4, acc1 = zero4;

  for (int c = 0; c < 16; ++c) {
    // stage V chunk transposed: VsT[d][k_local], 64 k-rows, b64 writes
    {
      const int kd = tid & 63;
      const int kg = tid >> 6;
      const float* vcol = Vp + (size_t)(c * 64 + kg * 16) * 512 + kd;
#pragma unroll
      for (int t4 = 0; t4 < 4; ++t4) {
        ushort4 w;
        w.x = f2bf(vcol[(size_t)(t4 * 4 + 0) * 512]);
        w.y = f2bf(vcol[(size_t)(t4 * 4 + 1) * 512]);
        w.z = f2bf(vcol[(size_t)(t4 * 4 + 2) * 512]);
        w.w = f2bf(vcol[(size_t)(t4 * 4 + 3) * 512]);
        *(ushort4*)(&VsT[kd * VSTR + kg * 16 + t4 * 4]) = w;
      }
    }
    __syncthreads();

#pragma unroll
    for (int kt = 0; kt < 2; ++kt) {
      int colk = c * 64 + kt * 32 + g * 8;
      int prow = m_o * 16 + li;
      short8 pa = *(const short8*)(pb + (((prow << 11) + (colk << 1)) ^ ((prow & 7) << 4)));
#pragma unroll
      for (int nn = 0; nn < 2; ++nn) {
        int d = nb_ + nn * 16 + li;
        short8 vbf = *(const short8*)(&VsT[d * VSTR + kt * 32 + g * 8]);
        if (nn == 0) acc0 = __builtin_amdgcn_mfma_f32_16x16x32_bf16(pa, vbf, acc0, 0, 0, 0);
        else         acc1 = __builtin_amdgcn_mfma_f32_16x16x32_bf16(pa, vbf, acc1, 0, 0, 0);
      }
    }
    __syncthreads();
  }

  // ---- epilogue: out[q0+m_o*16+g*4+r][nb_ + nn*16 + li], nt stores ----
#pragma unroll
  for (int r = 0; r < 4; ++r) {
    int row = q0 + m_o * 16 + g * 4 + r;
    __builtin_nontemporal_store(acc0[r], Outp + (size_t)row * 2048 + nb_ + li);
    __builtin_nontemporal_store(acc1[r], Outp + (size_t)row * 2048 + nb_ + 16 + li);
  }
}

extern "C" void kernel_launch(void* const* d_in, const int* in_sizes, int n_in,
                              void* d_out, int out_size, void* d_ws, size_t ws_size,
                              hipStream_t stream) {
  const float* q = (const float*)d_in[0];
  const float* k = (const float*)d_in[1];
  const float* v = (const float*)d_in[2];
  float* o = (float*)d_out;
  dim3 grid(NB * NH * (SEQ / QBLK));  // 4096
  dim3 block(256);
  hipLaunchKernelGGL(gqa_kernel, grid, block, 0, stream, q, k, v, o);
}

// Round 5
// 529.927 us; speedup vs baseline: 1.9251x; 1.6436x over previous
//
#include <hip/hip_runtime.h>

#define NB 4
#define SEQ 1024
#define NH 32
#define NKV 8
#define HD 64
#define QBLK 32
#define VSTR 72   // VsT row stride in ushorts (144B: 16B-aligned rows)

typedef __attribute__((ext_vector_type(8))) short short8;
typedef __attribute__((ext_vector_type(4))) float f32x4;
typedef __attribute__((ext_vector_type(4))) unsigned short u16x4;

static __device__ __forceinline__ unsigned short f2bf(float f) {
  union { float f; unsigned u; } x; x.f = f;
  unsigned u = x.u;
  u += 0x7fffu + ((u >> 16) & 1u);   // round-to-nearest-even
  return (unsigned short)(u >> 16);
}
static __device__ __forceinline__ float bf2f(unsigned short h) {
  union { unsigned u; float f; } x; x.u = ((unsigned)h) << 16;
  return x.f;
}

__global__ __launch_bounds__(512, 4) void gqa_kernel(
    const float* __restrict__ Qg, const float* __restrict__ Kg,
    const float* __restrict__ Vg, float* __restrict__ Og) {
  __shared__ unsigned short Ph[QBLK * 512];      // 32KB: bf16 P half, swizzled
  __shared__ unsigned short VsT[2][HD * VSTR];   // 2x9KB: V^T chunk, dbuf
  __shared__ float redmax[QBLK][8];
  __shared__ float redsum[QBLK][8];

  const int tid = threadIdx.x;
  const int lane = tid & 63;
  const int wid = tid >> 6;        // 0..7
  const int li = lane & 15;
  const int g = lane >> 4;

  // XCD-aware bijective swizzle: 4096 blocks, 8 XCDs -> 512 contiguous each.
  const int hw = blockIdx.x;
  const int gid = (hw & 7) * 512 + (hw >> 3);

  const int qt = gid & 31;
  const int h = (gid >> 5) & 31;
  const int b = gid >> 10;
  const int hkv = h >> 2;
  const int q0 = qt * QBLK;

  const float* Qp = Qg + ((size_t)b * SEQ) * 2048 + h * 64;
  const float* Kp = Kg + ((size_t)b * SEQ) * 512 + hkv * 64;
  const float* Vp = Vg + ((size_t)b * SEQ) * 512 + hkv * 64;
  float* Outp = Og + ((size_t)b * SEQ) * 2048 + h * 64;
  float* Attnp = Og + (size_t)NB * SEQ * 2048
               + (((size_t)(b * NH + h)) * SEQ + q0) * SEQ;

  char* phb = (char*)&Ph[0];

  // ---- Q fragments, scale 1/8 folded in fp32 (exact) ----
  short8 aq[2][2];
#pragma unroll
  for (int m = 0; m < 2; ++m)
#pragma unroll
    for (int dh = 0; dh < 2; ++dh) {
      const float* qp = Qp + (size_t)(q0 + m * 16 + li) * 2048 + dh * 32 + g * 8;
      float4 x = *(const float4*)qp;
      float4 y = *(const float4*)(qp + 4);
      short8 t;
      t[0] = (short)f2bf(x.x * 0.125f); t[1] = (short)f2bf(x.y * 0.125f);
      t[2] = (short)f2bf(x.z * 0.125f); t[3] = (short)f2bf(x.w * 0.125f);
      t[4] = (short)f2bf(y.x * 0.125f); t[5] = (short)f2bf(y.y * 0.125f);
      t[6] = (short)f2bf(y.z * 0.125f); t[7] = (short)f2bf(y.w * 0.125f);
      aq[m][dh] = t;
    }

  // ---- QK^T: wave owns 128 cols [wid*128, wid*128+128) ----
  f32x4 acc[2][8];
  f32x4 zero4 = {0.f, 0.f, 0.f, 0.f};
#pragma unroll
  for (int m = 0; m < 2; ++m)
#pragma unroll
    for (int j = 0; j < 8; ++j) acc[m][j] = zero4;

  const int colbase = wid * 128 + li;
#pragma unroll
  for (int j = 0; j < 8; ++j) {
    int col = colbase + j * 16;
    short8 bk[2];
#pragma unroll
    for (int dh = 0; dh < 2; ++dh) {
      const float* kp = Kp + (size_t)col * 512 + dh * 32 + g * 8;
      float4 x = *(const float4*)kp;
      float4 y = *(const float4*)(kp + 4);
      short8 t;
      t[0]=(short)f2bf(x.x); t[1]=(short)f2bf(x.y); t[2]=(short)f2bf(x.z); t[3]=(short)f2bf(x.w);
      t[4]=(short)f2bf(y.x); t[5]=(short)f2bf(y.y); t[6]=(short)f2bf(y.z); t[7]=(short)f2bf(y.w);
      bk[dh] = t;
    }
#pragma unroll
    for (int m = 0; m < 2; ++m) {
      acc[m][j] = __builtin_amdgcn_mfma_f32_16x16x32_bf16(aq[m][0], bk[0], acc[m][j], 0, 0, 0);
      acc[m][j] = __builtin_amdgcn_mfma_f32_16x16x32_bf16(aq[m][1], bk[1], acc[m][j], 0, 0, 0);
    }
  }

  // ---- softmax stats (C layout: row=(lane>>4)*4+r, col=lane&15) ----
#pragma unroll
  for (int m = 0; m < 2; ++m)
#pragma unroll
    for (int r = 0; r < 4; ++r) {
      float mx = -1e30f;
#pragma unroll
      for (int j = 0; j < 8; ++j) mx = fmaxf(mx, acc[m][j][r]);
      mx = fmaxf(mx, __shfl_xor(mx, 1));
      mx = fmaxf(mx, __shfl_xor(mx, 2));
      mx = fmaxf(mx, __shfl_xor(mx, 4));
      mx = fmaxf(mx, __shfl_xor(mx, 8));
      if (li == 0) redmax[m * 16 + g * 4 + r][wid] = mx;
    }
  __syncthreads();

#pragma unroll
  for (int m = 0; m < 2; ++m)
#pragma unroll
    for (int r = 0; r < 4; ++r) {
      int row = m * 16 + g * 4 + r;
      float mx = fmaxf(fmaxf(fmaxf(redmax[row][0], redmax[row][1]),
                             fmaxf(redmax[row][2], redmax[row][3])),
                       fmaxf(fmaxf(redmax[row][4], redmax[row][5]),
                             fmaxf(redmax[row][6], redmax[row][7])));
      float s = 0.f;
#pragma unroll
      for (int j = 0; j < 8; ++j) {
        float e = __expf(acc[m][j][r] - mx);
        acc[m][j][r] = e;
        s += e;
      }
      s += __shfl_xor(s, 1);
      s += __shfl_xor(s, 2);
      s += __shfl_xor(s, 4);
      s += __shfl_xor(s, 8);
      if (li == 0) redsum[row][wid] = s;
    }
  __syncthreads();

  // ---- normalize in registers ----
#pragma unroll
  for (int m = 0; m < 2; ++m)
#pragma unroll
    for (int r = 0; r < 4; ++r) {
      int row = m * 16 + g * 4 + r;
      float L = 0.f;
#pragma unroll
      for (int w = 0; w < 8; ++w) L += redsum[row][w];
      float inv = 1.0f / L;
#pragma unroll
      for (int j = 0; j < 8; ++j) acc[m][j][r] *= inv;
    }

  // ---- PV + attn store, one 512-col half at a time ----
  const int m_o = wid >> 2;          // out row tile 0/1
  const int nb_ = (wid & 3) * 16;    // out col tile
  f32x4 oacc = zero4;

  const int kd = tid & 63;   // d index for V staging
  const int kg = tid >> 6;   // k-group 0..7

  for (int h2 = 0; h2 < 2; ++h2) {
    // P strips of this half -> LDS (waves wid>>2 == h2 own cols h2*512..+511)
    if ((wid >> 2) == h2) {
      int cb = (wid & 3) * 128 + li;  // col within half
#pragma unroll
      for (int m = 0; m < 2; ++m)
#pragma unroll
        for (int r = 0; r < 4; ++r) {
          int row = m * 16 + g * 4 + r;
#pragma unroll
          for (int j = 0; j < 8; ++j) {
            int col = cb + j * 16;
            *(unsigned short*)(phb + (((row << 10) + (col << 1)) ^ ((row & 7) << 4)))
                = f2bf(acc[m][j][r]);
          }
        }
    }
    // stage first V chunk of this half into buf 0
    {
      int cc = h2 * 8;
      const float* vcol = Vp + (size_t)(cc * 64 + kg * 8) * 512 + kd;
      float pv[8];
#pragma unroll
      for (int i = 0; i < 8; ++i) pv[i] = vcol[(size_t)i * 512];
      ushort4 w0, w1;
      w0.x = f2bf(pv[0]); w0.y = f2bf(pv[1]); w0.z = f2bf(pv[2]); w0.w = f2bf(pv[3]);
      w1.x = f2bf(pv[4]); w1.y = f2bf(pv[5]); w1.z = f2bf(pv[6]); w1.w = f2bf(pv[7]);
      *(ushort4*)(&VsT[0][kd * VSTR + kg * 8]) = w0;
      *(ushort4*)(&VsT[0][kd * VSTR + kg * 8 + 4]) = w1;
    }
    __syncthreads();

    // attn store: full-line nt f32x4 (64 lanes x 16B = 1KB contiguous/instr)
    {
      int rsub = tid >> 7;          // 0..3
      int c128 = tid & 127;
#pragma unroll
      for (int i = 0; i < 8; ++i) {
        int row = i * 4 + rsub;
        u16x4 u = *(const u16x4*)(phb + (((row << 10) + (c128 << 3)) ^ ((row & 7) << 4)));
        f32x4 f;
        f.x = bf2f(u.x); f.y = bf2f(u.y); f.z = bf2f(u.z); f.w = bf2f(u.w);
        __builtin_nontemporal_store(f, (f32x4*)(Attnp + (size_t)row * SEQ + h2 * 512 + c128 * 4));
      }
    }

    // PV chunk loop with double-buffered V prefetch
    for (int c = 0; c < 8; ++c) {
      float pv[8];
      if (c < 7) {
        int cc = h2 * 8 + c + 1;
        const float* vcol = Vp + (size_t)(cc * 64 + kg * 8) * 512 + kd;
#pragma unroll
        for (int i = 0; i < 8; ++i) pv[i] = vcol[(size_t)i * 512];
      }
      const unsigned short* vbuf = &VsT[c & 1][0];
#pragma unroll
      for (int kt = 0; kt < 2; ++kt) {
        int lcol = c * 64 + kt * 32 + g * 8;
        int prow = m_o * 16 + li;
        short8 pa = *(const short8*)(phb + (((prow << 10) + (lcol << 1)) ^ ((prow & 7) << 4)));
        short8 vbf = *(const short8*)(&vbuf[(nb_ + li) * VSTR + kt * 32 + g * 8]);
        oacc = __builtin_amdgcn_mfma_f32_16x16x32_bf16(pa, vbf, oacc, 0, 0, 0);
      }
      if (c < 7) {
        ushort4 w0, w1;
        w0.x = f2bf(pv[0]); w0.y = f2bf(pv[1]); w0.z = f2bf(pv[2]); w0.w = f2bf(pv[3]);
        w1.x = f2bf(pv[4]); w1.y = f2bf(pv[5]); w1.z = f2bf(pv[6]); w1.w = f2bf(pv[7]);
        unsigned short* dst = &VsT[(c + 1) & 1][kd * VSTR + kg * 8];
        *(ushort4*)(dst) = w0;
        *(ushort4*)(dst + 4) = w1;
      }
      __syncthreads();
    }
  }

  // ---- epilogue: out[q0 + m_o*16 + g*4 + r][nb_ + li], nt ----
#pragma unroll
  for (int r = 0; r < 4; ++r) {
    int row = q0 + m_o * 16 + g * 4 + r;
    __builtin_nontemporal_store(oacc[r], Outp + (size_t)row * 2048 + nb_ + li);
  }
}

extern "C" void kernel_launch(void* const* d_in, const int* in_sizes, int n_in,
                              void* d_out, int out_size, void* d_ws, size_t ws_size,
                              hipStream_t stream) {
  const float* q = (const float*)d_in[0];
  const float* k = (const float*)d_in[1];
  const float* v = (const float*)d_in[2];
  float* o = (float*)d_out;
  dim3 grid(NB * NH * (SEQ / QBLK));  // 4096
  dim3 block(512);
  hipLaunchKernelGGL(gqa_kernel, grid, block, 0, stream, q, k, v, o);
}